// Round 1
// baseline (34486.749 us; speedup 1.0000x reference)
//
#include <hip/hip_runtime.h>
#include <math.h>

// Problem constants
#define KV 2048
#define KE 512
#define KH 1024
#define KB 128
#define KL 256
#define KH3 3072
#define TCHUNK 32

// ---------------------------------------------------------------------------
// Generic C = A(M,K) @ B(N,K)^T  (+bias[n]) (+addrow[row%128, n]) (+=) with
// optional scatter of output rows to d_out[(b*L + t0+tl+1)*V + n].
// 64x64 tile, 256 threads, 4x4 micro-tile, BK=16, float4 LDS reads.
// Requires M%64==0, N%64==0, K%16==0 (all shapes here satisfy this).
// ---------------------------------------------------------------------------
__global__ __launch_bounds__(256)
void gemm_bt(const float* __restrict__ A, int lda,
             const float* __restrict__ Bm, int ldb,
             float* __restrict__ Out, int N, int K,
             const float* __restrict__ bias,
             const float* __restrict__ addrow,
             int accumulate, int scatter, int t0)
{
    __shared__ float As[16][68];
    __shared__ float Bs[16][68];
    const int tid = threadIdx.x;
    const int m0 = blockIdx.y * 64;
    const int n0 = blockIdx.x * 64;
    const int tx = tid & 15, ty = tid >> 4;
    const int ldrow = tid >> 2;          // 0..63
    const int kcol  = (tid & 3) << 2;    // 0,4,8,12
    const float* Ap = A + (size_t)(m0 + ldrow) * lda + kcol;
    const float* Bp = Bm + (size_t)(n0 + ldrow) * ldb + kcol;
    float acc[4][4] = {};
    for (int k0 = 0; k0 < K; k0 += 16) {
        const float4 av = *(const float4*)(Ap + k0);
        const float4 bv = *(const float4*)(Bp + k0);
        As[kcol + 0][ldrow] = av.x;
        As[kcol + 1][ldrow] = av.y;
        As[kcol + 2][ldrow] = av.z;
        As[kcol + 3][ldrow] = av.w;
        Bs[kcol + 0][ldrow] = bv.x;
        Bs[kcol + 1][ldrow] = bv.y;
        Bs[kcol + 2][ldrow] = bv.z;
        Bs[kcol + 3][ldrow] = bv.w;
        __syncthreads();
        #pragma unroll
        for (int k = 0; k < 16; ++k) {
            const float4 a = *(const float4*)(&As[k][ty << 2]);
            const float4 b = *(const float4*)(&Bs[k][tx << 2]);
            const float ar[4] = {a.x, a.y, a.z, a.w};
            const float br[4] = {b.x, b.y, b.z, b.w};
            #pragma unroll
            for (int i = 0; i < 4; ++i)
                #pragma unroll
                for (int j = 0; j < 4; ++j)
                    acc[i][j] = fmaf(ar[i], br[j], acc[i][j]);
        }
        __syncthreads();
    }
    #pragma unroll
    for (int i = 0; i < 4; ++i) {
        const int row = m0 + (ty << 2) + i;
        float* orow;
        if (scatter) {
            const int b  = row & (KB - 1);   // chunk rows are (tl, b)
            const int tl = row >> 7;
            orow = Out + (size_t)(b * KL + t0 + tl + 1) * KV;
        } else {
            orow = Out + (size_t)row * N;
        }
        const int col = n0 + (tx << 2);
        #pragma unroll
        for (int j = 0; j < 4; ++j) {
            float v = acc[i][j];
            if (bias)       v += bias[col + j];
            if (addrow)     v += addrow[(size_t)(row & (KB - 1)) * N + col + j];
            if (accumulate) v += orow[col + j];
            orow[col + j] = v;
        }
    }
}

// X[tl, b, :] = emb[seq[b, t0+tl], :]   (float4 granularity, E/4 = 128)
__global__ __launch_bounds__(256)
void gather_emb(const float4* __restrict__ emb, const int* __restrict__ seq,
                float4* __restrict__ X, int t0)
{
    const int idx = blockIdx.x * 256 + threadIdx.x;  // Tc*B*128
    const int e4 = idx & 127;
    const int r  = idx >> 7;
    const int b  = r & (KB - 1);
    const int tl = r >> 7;
    const int tok = seq[b * KL + t0 + tl];
    X[idx] = emb[(size_t)tok * 128 + e4];
}

// GRU cell elementwise. gi: (B,3H) input-gate pre-acts (+ b_ih for encoder;
// decoder adds ci = context @ W_ih_d[:,E:]^T + b_ih_d). gh: (B,3H) = h@W_hh^T + b_hh.
__global__ __launch_bounds__(256)
void gru_ew(float* __restrict__ h, const float* __restrict__ gi,
            const float* __restrict__ ci, const float* __restrict__ gh,
            float* __restrict__ h2out)
{
    const int idx = blockIdx.x * 256 + threadIdx.x;  // B*H
    const int b = idx >> 10, i = idx & (KH - 1);
    const int base = b * KH3 + i;
    float ir = gi[base], iz = gi[base + KH], inn = gi[base + 2 * KH];
    if (ci) { ir += ci[base]; iz += ci[base + KH]; inn += ci[base + 2 * KH]; }
    const float hr = gh[base], hz = gh[base + KH], hn = gh[base + 2 * KH];
    const float r = 1.0f / (1.0f + expf(-(ir + hr)));
    const float z = 1.0f / (1.0f + expf(-(iz + hz)));
    const float n = tanhf(inn + r * hn);
    const float hv = h[idx];
    const float hnew = (1.0f - z) * n + z * hv;
    h[idx] = hnew;
    if (h2out) h2out[idx] = hnew;
}

__global__ __launch_bounds__(256)
void zero_f32(float* __restrict__ p, int n)
{
    const int i = blockIdx.x * 256 + threadIdx.x;
    if (i < n) p[i] = 0.0f;
}

// outputs[:, 0, :] = 0
__global__ __launch_bounds__(256)
void zero_row0(float* __restrict__ out)
{
    const int idx = blockIdx.x * 256 + threadIdx.x;  // B*V
    const int b = idx >> 11, v = idx & (KV - 1);
    out[(size_t)b * KL * KV + v] = 0.0f;
}

__global__ __launch_bounds__(256)
void copy_f32(float* __restrict__ dst, const float* __restrict__ src, int n)
{
    const int i = blockIdx.x * 256 + threadIdx.x;
    if (i < n) dst[i] = src[i];
}

extern "C" void kernel_launch(void* const* d_in, const int* in_sizes, int n_in,
                              void* d_out, int out_size, void* d_ws, size_t ws_size,
                              hipStream_t stream)
{
    (void)in_sizes; (void)n_in; (void)out_size; (void)ws_size;
    const int*   seq     = (const int*)  d_in[0];
    // d_in[1] = teacher_forcing_ratio (unused: reference always teacher-forces)
    const float* emb_enc = (const float*)d_in[2];
    const float* W_ih_e  = (const float*)d_in[3];
    const float* W_hh_e  = (const float*)d_in[4];
    const float* b_ih_e  = (const float*)d_in[5];
    const float* b_hh_e  = (const float*)d_in[6];
    const float* emb_dec = (const float*)d_in[7];
    const float* W_ih_d  = (const float*)d_in[8];   // (3H, E+H)
    const float* W_hh_d  = (const float*)d_in[9];
    const float* b_ih_d  = (const float*)d_in[10];
    const float* b_hh_d  = (const float*)d_in[11];
    const float* fc_W    = (const float*)d_in[12];  // (V, E+2H)
    const float* fc_b    = (const float*)d_in[13];
    float* out = (float*)d_out;

    // Workspace layout (floats), total ~20.05M floats = 80.2 MB
    float* ws  = (float*)d_ws;
    float* h   = ws;                         // B*H      = 131072
    float* gh  = h   + KB * KH;              // B*3H     = 393216
    float* ci  = gh  + KB * KH3;             // B*3H     = 393216
    float* cf  = ci  + KB * KH3;             // B*V      = 262144
    float* Xc  = cf  + KB * KV;              // 32*B*E   = 2097152
    float* gic = Xc  + TCHUNK * KB * KE;     // 32*B*3H  = 12582912
    float* h2c = gic + TCHUNK * KB * KH3;    // 32*B*H   = 4194304

    // h0 = 0
    zero_f32<<<(KB * KH) / 256, 256, 0, stream>>>(h, KB * KH);

    // ---------------- Encoder ----------------
    for (int t0 = 0; t0 < KL; t0 += TCHUNK) {
        gather_emb<<<(TCHUNK * KB * (KE / 4)) / 256, 256, 0, stream>>>(
            (const float4*)emb_enc, seq, (float4*)Xc, t0);
        // gi = X @ W_ih_e^T + b_ih_e   (M=4096, N=3072, K=512)
        gemm_bt<<<dim3(KH3 / 64, (TCHUNK * KB) / 64), 256, 0, stream>>>(
            Xc, KE, W_ih_e, KE, gic, KH3, KE, b_ih_e, nullptr, 0, 0, 0);
        for (int tl = 0; tl < TCHUNK; ++tl) {
            // gh = h @ W_hh_e^T + b_hh_e  (M=128, N=3072, K=1024)
            gemm_bt<<<dim3(KH3 / 64, KB / 64), 256, 0, stream>>>(
                h, KH, W_hh_e, KH, gh, KH3, KH, b_hh_e, nullptr, 0, 0, 0);
            gru_ew<<<(KB * KH) / 256, 256, 0, stream>>>(
                h, gic + (size_t)tl * KB * KH3, nullptr, gh, nullptr);
        }
    }

    // context -> d_out; mu = log_var = 0; outputs[:,0,:] = 0
    float* ctx_out = out + (size_t)KB * KL * KV;
    copy_f32<<<(KB * KH) / 256, 256, 0, stream>>>(ctx_out, h, KB * KH);
    zero_f32<<<(2 * KB * KH) / 256, 256, 0, stream>>>(ctx_out + KB * KH, 2 * KB * KH);
    zero_row0<<<(KB * KV) / 256, 256, 0, stream>>>(out);

    // Loop-invariant context terms:
    // ci = context @ W_ih_d[:, E:]^T + b_ih_d   (M=128, N=3072, K=1024)
    gemm_bt<<<dim3(KH3 / 64, KB / 64), 256, 0, stream>>>(
        h, KH, W_ih_d + KE, KE + KH, ci, KH3, KH, b_ih_d, nullptr, 0, 0, 0);
    // cf = context @ fc_W[:, E+H:]^T + fc_b     (M=128, N=2048, K=1024)
    gemm_bt<<<dim3(KV / 64, KB / 64), 256, 0, stream>>>(
        h, KH, fc_W + (KE + KH), KE + 2 * KH, cf, KV, KH, fc_b, nullptr, 0, 0, 0);

    // ---------------- Decoder ---------------- (h currently = context)
    for (int t0 = 0; t0 < KL - 1; t0 += TCHUNK) {
        const int Tc = ((KL - 1 - t0) < TCHUNK) ? (KL - 1 - t0) : TCHUNK;
        gather_emb<<<(Tc * KB * (KE / 4)) / 256, 256, 0, stream>>>(
            (const float4*)emb_dec, seq, (float4*)Xc, t0);
        // gi = E_chunk @ W_ih_d[:, :E]^T (no bias; bias lives in ci)
        gemm_bt<<<dim3(KH3 / 64, (Tc * KB) / 64), 256, 0, stream>>>(
            Xc, KE, W_ih_d, KE + KH, gic, KH3, KE, nullptr, nullptr, 0, 0, 0);
        for (int tl = 0; tl < Tc; ++tl) {
            gemm_bt<<<dim3(KH3 / 64, KB / 64), 256, 0, stream>>>(
                h, KH, W_hh_d, KH, gh, KH3, KH, b_hh_d, nullptr, 0, 0, 0);
            gru_ew<<<(KB * KH) / 256, 256, 0, stream>>>(
                h, gic + (size_t)tl * KB * KH3, ci, gh, h2c + (size_t)tl * KB * KH);
        }
        // preds = E_chunk @ fc_W[:, :E]^T + cf[b]  (scatter to out rows t0+tl+1)
        gemm_bt<<<dim3(KV / 64, (Tc * KB) / 64), 256, 0, stream>>>(
            Xc, KE, fc_W, KE + 2 * KH, out, KV, KE, nullptr, cf, 0, 1, t0);
        // preds += h2_chunk @ fc_W[:, E:E+H]^T
        gemm_bt<<<dim3(KV / 64, (Tc * KB) / 64), 256, 0, stream>>>(
            h2c, KH, fc_W + KE, KE + 2 * KH, out, KV, KH, nullptr, nullptr, 1, 1, t0);
    }
}

// Round 2
// 9128.291 us; speedup vs baseline: 3.7780x; 3.7780x over previous
//
#include <hip/hip_runtime.h>
#include <math.h>

#define KV 2048
#define KE 512
#define KH 1024
#define KB 128
#define KL 256
#define KH3 3072
#define TCH 32

typedef __attribute__((ext_vector_type(8))) short s8v;     // 8 bf16 (4 VGPRs)
typedef __attribute__((ext_vector_type(8))) unsigned short u16x8;
typedef __attribute__((ext_vector_type(4))) float f4v;

__device__ __forceinline__ unsigned short f2b(float f) {   // fp32 -> bf16 RNE
    unsigned u = __float_as_uint(f);
    u += 0x7fffu + ((u >> 16) & 1u);
    return (unsigned short)(u >> 16);
}
__device__ __forceinline__ float b2f(unsigned short h) {
    return __uint_as_float(((unsigned)h) << 16);
}

// ---------------------------------------------------------------------------
// Stage ROWS x 64 bf16 tile (row-major, 128B rows) global -> LDS via
// global_load_lds width=16, with XOR-8 chunk swizzle: global chunk c of row r
// stored at LDS slot (c ^ (r&7)). Wave-load = 8 rows (64 lanes x 16B = 1KB).
// ---------------------------------------------------------------------------
template<int ROWS>
__device__ __forceinline__ void stage_tile(unsigned short* lds,
                                           const unsigned short* g, int ld)
{
    const int tid = threadIdx.x;
    const int wave = tid >> 6, lane = tid & 63;
    constexpr int per_wave = ROWS / 32;
    #pragma unroll
    for (int i = 0; i < per_wave; ++i) {
        const int r0 = (wave * per_wave + i) * 8;
        const int r  = r0 + (lane >> 3);
        const int cg = (lane & 7) ^ (r & 7);
        const unsigned short* gp = g + (size_t)r * ld + cg * 8;
        __builtin_amdgcn_global_load_lds(
            (const __attribute__((address_space(1))) unsigned int*)(const void*)gp,
            (__attribute__((address_space(3))) unsigned int*)(void*)(lds + r0 * 64),
            16, 0, 0);
    }
}

// ---------------------------------------------------------------------------
// C(M,N) = A(M,K) @ B(N,K)^T [bf16 in, fp32 acc]. BM=128 BN=128 BK=64,
// 4 waves 2x2, each wave 64x64 = 4x4 MFMA frags. Optional bias[n],
// addrow[row&127][n], scatter (out[(b*L+t0+tl+1)*V + n]), bf16 or f32 store.
// ---------------------------------------------------------------------------
__global__ __launch_bounds__(256)
void gemm128(const unsigned short* __restrict__ A, int lda,
             const unsigned short* __restrict__ Bm, int ldb,
             float* __restrict__ OutF, unsigned short* __restrict__ OutH,
             int N, int K,
             const float* __restrict__ bias,
             const float* __restrict__ addrow,
             int scatter, int t0)
{
    __shared__ unsigned short As[128 * 64];
    __shared__ unsigned short Bs[128 * 64];
    const int tid = threadIdx.x;
    const int wave = tid >> 6, lane = tid & 63;
    const int wm = wave >> 1, wn = wave & 1;
    const int q = lane >> 4, l15 = lane & 15, l7 = lane & 7;
    const int m0 = blockIdx.y * 128, n0 = blockIdx.x * 128;
    f4v acc[4][4] = {};
    for (int kb = 0; kb < K; kb += 64) {
        stage_tile<128>(As, A + (size_t)m0 * lda + kb, lda);
        stage_tile<128>(Bs, Bm + (size_t)n0 * ldb + kb, ldb);
        __syncthreads();
        #pragma unroll
        for (int kk = 0; kk < 2; ++kk) {
            const int ch = (kk * 4 + q) ^ l7;
            s8v a[4], b[4];
            #pragma unroll
            for (int i = 0; i < 4; ++i) {
                a[i] = *(const s8v*)(As + (wm * 64 + i * 16 + l15) * 64 + ch * 8);
                b[i] = *(const s8v*)(Bs + (wn * 64 + i * 16 + l15) * 64 + ch * 8);
            }
            #pragma unroll
            for (int i = 0; i < 4; ++i)
                #pragma unroll
                for (int j = 0; j < 4; ++j)
                    acc[i][j] = __builtin_amdgcn_mfma_f32_16x16x32_bf16(
                        a[i], b[j], acc[i][j], 0, 0, 0);
        }
        __syncthreads();
    }
    #pragma unroll
    for (int i = 0; i < 4; ++i) {
        #pragma unroll
        for (int r = 0; r < 4; ++r) {
            const int row = m0 + wm * 64 + i * 16 + q * 4 + r;
            size_t obase;
            if (scatter) {
                const int bidx = row & 127, tl = row >> 7;
                obase = (size_t)(bidx * KL + t0 + tl + 1) * KV;
            } else {
                obase = (size_t)row * N;
            }
            #pragma unroll
            for (int j = 0; j < 4; ++j) {
                const int col = n0 + wn * 64 + j * 16 + l15;
                float v = acc[i][j][r];
                if (bias)   v += bias[col];
                if (addrow) v += addrow[(size_t)(row & 127) * N + col];
                if (OutF) OutF[obase + col] = v;
                else      OutH[obase + col] = f2b(v);
            }
        }
    }
}

// ---------------------------------------------------------------------------
// Recurrent GEMM: gh(128,N) = h(128,K) @ W(N,K)^T + b_hh. BM=128 (whole M),
// BN=32, BK=64 -> grid N/32 = 96 blocks. Wave w: rows w*32..+32, 2x2 frags.
// ---------------------------------------------------------------------------
__global__ __launch_bounds__(256)
void rec_gemm(const unsigned short* __restrict__ A,
              const unsigned short* __restrict__ Bm,
              float* __restrict__ Out, int N, int K,
              const float* __restrict__ bias)
{
    __shared__ unsigned short As[128 * 64];
    __shared__ unsigned short Bs[32 * 64];
    const int tid = threadIdx.x;
    const int wave = tid >> 6, lane = tid & 63;
    const int q = lane >> 4, l15 = lane & 15, l7 = lane & 7;
    const int n0 = blockIdx.x * 32;
    f4v acc[2][2] = {};
    for (int kb = 0; kb < K; kb += 64) {
        stage_tile<128>(As, A + kb, K);
        stage_tile<32>(Bs, Bm + (size_t)n0 * K + kb, K);
        __syncthreads();
        #pragma unroll
        for (int kk = 0; kk < 2; ++kk) {
            const int ch = (kk * 4 + q) ^ l7;
            s8v a[2], b[2];
            #pragma unroll
            for (int i = 0; i < 2; ++i) {
                a[i] = *(const s8v*)(As + (wave * 32 + i * 16 + l15) * 64 + ch * 8);
                b[i] = *(const s8v*)(Bs + (i * 16 + l15) * 64 + ch * 8);
            }
            #pragma unroll
            for (int i = 0; i < 2; ++i)
                #pragma unroll
                for (int j = 0; j < 2; ++j)
                    acc[i][j] = __builtin_amdgcn_mfma_f32_16x16x32_bf16(
                        a[i], b[j], acc[i][j], 0, 0, 0);
        }
        __syncthreads();
    }
    #pragma unroll
    for (int i = 0; i < 2; ++i) {
        #pragma unroll
        for (int r = 0; r < 4; ++r) {
            const int row = wave * 32 + i * 16 + q * 4 + r;
            #pragma unroll
            for (int j = 0; j < 2; ++j) {
                const int col = n0 + j * 16 + l15;
                Out[(size_t)row * N + col] = acc[i][j][r] + bias[col];
            }
        }
    }
}

// GRU cell elementwise. gi bf16 (pre-acts incl. b_ih for encoder); ci fp32
// nullable (decoder: context@W_ih_d[:,E:]^T + b_ih_d); gh fp32 (incl. b_hh).
// Writes h fp32, hb bf16, optional h2 bf16 into featc (ld 1536, col 512).
__global__ __launch_bounds__(256)
void gru_ew(float* __restrict__ h, unsigned short* __restrict__ hb,
            const unsigned short* __restrict__ gi,
            const float* __restrict__ ci,
            const float* __restrict__ gh,
            unsigned short* __restrict__ h2out)
{
    const int idx = blockIdx.x * 256 + threadIdx.x;   // B*H
    const int b = idx >> 10, i = idx & (KH - 1);
    const size_t base = (size_t)b * KH3 + i;
    float ir = b2f(gi[base]);
    float iz = b2f(gi[base + KH]);
    float in = b2f(gi[base + 2 * KH]);
    if (ci) { ir += ci[base]; iz += ci[base + KH]; in += ci[base + 2 * KH]; }
    const float hr = gh[base], hz = gh[base + KH], hn = gh[base + 2 * KH];
    const float r = 1.0f / (1.0f + __expf(-(ir + hr)));
    const float z = 1.0f / (1.0f + __expf(-(iz + hz)));
    const float n = tanhf(in + r * hn);
    const float hnew = (1.0f - z) * n + z * h[idx];
    h[idx] = hnew;
    hb[idx] = f2b(hnew);
    if (h2out) h2out[(size_t)b * (KE + KH) + i] = f2b(hnew);
}

// X[tl*128+b, 0:512] = bf16(emb[seq[b, t0+tl], :]), row stride ldx
__global__ __launch_bounds__(256)
void gather_emb(const float* __restrict__ emb, const int* __restrict__ seq,
                unsigned short* __restrict__ X, int ldx, int t0)
{
    const int idx = blockIdx.x * 256 + threadIdx.x;   // Tc*B*64
    const int e8 = idx & 63;
    const int rr = idx >> 6;
    const int b = rr & 127, tl = rr >> 7;
    const int tok = seq[b * KL + t0 + tl];
    const float4* src = (const float4*)(emb + (size_t)tok * KE + e8 * 8);
    const float4 v0 = src[0], v1 = src[1];
    u16x8 o;
    o[0] = f2b(v0.x); o[1] = f2b(v0.y); o[2] = f2b(v0.z); o[3] = f2b(v0.w);
    o[4] = f2b(v1.x); o[5] = f2b(v1.y); o[6] = f2b(v1.z); o[7] = f2b(v1.w);
    *(u16x8*)(X + (size_t)rr * ldx + e8 * 8) = o;
}

__global__ __launch_bounds__(256)
void f32tobf16(const float* __restrict__ src, unsigned short* __restrict__ dst, int n)
{
    const int i = (blockIdx.x * 256 + threadIdx.x) * 4;
    if (i < n) {
        const float4 v = *(const float4*)(src + i);
        dst[i] = f2b(v.x); dst[i + 1] = f2b(v.y);
        dst[i + 2] = f2b(v.z); dst[i + 3] = f2b(v.w);
    }
}

__global__ __launch_bounds__(256)
void zero_f32(float* __restrict__ p, int n)
{
    const int i = blockIdx.x * 256 + threadIdx.x;
    if (i < n) p[i] = 0.0f;
}

__global__ __launch_bounds__(256)
void zero_u16(unsigned short* __restrict__ p, int n)
{
    const int i = blockIdx.x * 256 + threadIdx.x;
    if (i < n) p[i] = 0;
}

__global__ __launch_bounds__(256)
void copy_f32(float* __restrict__ dst, const float* __restrict__ src, int n)
{
    const int i = blockIdx.x * 256 + threadIdx.x;
    if (i < n) dst[i] = src[i];
}

__global__ __launch_bounds__(256)
void zero_row0(float* __restrict__ out)
{
    const int idx = blockIdx.x * 256 + threadIdx.x;   // B*V
    const int b = idx >> 11, v = idx & (KV - 1);
    out[(size_t)b * KL * KV + v] = 0.0f;
}

extern "C" void kernel_launch(void* const* d_in, const int* in_sizes, int n_in,
                              void* d_out, int out_size, void* d_ws, size_t ws_size,
                              hipStream_t stream)
{
    (void)in_sizes; (void)n_in; (void)out_size; (void)ws_size;
    const int*   seq     = (const int*)  d_in[0];
    const float* emb_enc = (const float*)d_in[2];
    const float* W_ih_e  = (const float*)d_in[3];
    const float* W_hh_e  = (const float*)d_in[4];
    const float* b_ih_e  = (const float*)d_in[5];
    const float* b_hh_e  = (const float*)d_in[6];
    const float* emb_dec = (const float*)d_in[7];
    const float* W_ih_d  = (const float*)d_in[8];   // (3H, E+H)
    const float* W_hh_d  = (const float*)d_in[9];
    const float* b_ih_d  = (const float*)d_in[10];
    const float* b_hh_d  = (const float*)d_in[11];
    const float* fc_W    = (const float*)d_in[12];  // (V, E+2H)
    const float* fc_b    = (const float*)d_in[13];
    float* out = (float*)d_out;

    // ---- workspace layout (78.4 MB) ----
    char* w = (char*)d_ws;
    unsigned short* Wb_ih_e = (unsigned short*)w;            w += (size_t)KH3 * KE * 2;
    unsigned short* Wb_hh_e = (unsigned short*)w;            w += (size_t)KH3 * KH * 2;
    unsigned short* Wb_ih_d = (unsigned short*)w;            w += (size_t)KH3 * (KE + KH) * 2;
    unsigned short* Wb_hh_d = (unsigned short*)w;            w += (size_t)KH3 * KH * 2;
    unsigned short* fc_Wb   = (unsigned short*)w;            w += (size_t)KV * (KE + 2 * KH) * 2;
    float*          h       = (float*)w;                     w += (size_t)KB * KH * 4;
    unsigned short* hb      = (unsigned short*)w;            w += (size_t)KB * KH * 2;
    float*          gh      = (float*)w;                     w += (size_t)KB * KH3 * 4;
    float*          ci      = (float*)w;                     w += (size_t)KB * KH3 * 4;
    float*          cf      = (float*)w;                     w += (size_t)KB * KV * 4;
    unsigned short* gi      = (unsigned short*)w;            w += (size_t)TCH * KB * KH3 * 2;
    unsigned short* featc   = (unsigned short*)w;            w += (size_t)TCH * KB * (KE + KH) * 2;

    // ---- weight conversion to bf16 ----
    f32tobf16<<<(KH3 * KE) / 1024, 256, 0, stream>>>(W_ih_e, Wb_ih_e, KH3 * KE);
    f32tobf16<<<(KH3 * KH) / 1024, 256, 0, stream>>>(W_hh_e, Wb_hh_e, KH3 * KH);
    f32tobf16<<<(KH3 * (KE + KH)) / 1024, 256, 0, stream>>>(W_ih_d, Wb_ih_d, KH3 * (KE + KH));
    f32tobf16<<<(KH3 * KH) / 1024, 256, 0, stream>>>(W_hh_d, Wb_hh_d, KH3 * KH);
    f32tobf16<<<(KV * (KE + 2 * KH)) / 1024, 256, 0, stream>>>(fc_W, fc_Wb, KV * (KE + 2 * KH));

    zero_f32<<<(KB * KH) / 256, 256, 0, stream>>>(h, KB * KH);
    zero_u16<<<(KB * KH) / 256, 256, 0, stream>>>(hb, KB * KH);

    // ---------------- Encoder ----------------
    for (int t0 = 0; t0 < KL; t0 += TCH) {
        // Xc = bf16 embeddings (reuse featc region, ld=512)
        unsigned short* Xc = featc;
        gather_emb<<<(TCH * KB * 64) / 256, 256, 0, stream>>>(emb_enc, seq, Xc, KE, t0);
        // gi = Xc @ W_ih_e^T + b_ih_e   (M=4096, N=3072, K=512) -> bf16
        gemm128<<<dim3(KH3 / 128, (TCH * KB) / 128), 256, 0, stream>>>(
            Xc, KE, Wb_ih_e, KE, nullptr, gi, KH3, KE, b_ih_e, nullptr, 0, 0);
        for (int tl = 0; tl < TCH; ++tl) {
            rec_gemm<<<KH3 / 32, 256, 0, stream>>>(hb, Wb_hh_e, gh, KH3, KH, b_hh_e);
            gru_ew<<<(KB * KH) / 256, 256, 0, stream>>>(
                h, hb, gi + (size_t)tl * KB * KH3, nullptr, gh, nullptr);
        }
    }

    // context -> d_out; mu = log_var = 0; outputs[:,0,:] = 0
    float* ctx_out = out + (size_t)KB * KL * KV;
    copy_f32<<<(KB * KH) / 256, 256, 0, stream>>>(ctx_out, h, KB * KH);
    zero_f32<<<(2 * KB * KH) / 256, 256, 0, stream>>>(ctx_out + KB * KH, 2 * KB * KH);
    zero_row0<<<(KB * KV) / 256, 256, 0, stream>>>(out);

    // ci = context @ W_ih_d[:, E:]^T + b_ih_d   (M=128, N=3072, K=1024)
    gemm128<<<dim3(KH3 / 128, 1), 256, 0, stream>>>(
        hb, KH, Wb_ih_d + KE, KE + KH, ci, nullptr, KH3, KH, b_ih_d, nullptr, 0, 0);
    // cf = context @ fc_W[:, E+H:]^T + fc_b     (M=128, N=2048, K=1024)
    gemm128<<<dim3(KV / 128, 1), 256, 0, stream>>>(
        hb, KH, fc_Wb + (KE + KH), KE + 2 * KH, cf, nullptr, KV, KH, fc_b, nullptr, 0, 0);

    // ---------------- Decoder ---------------- (h/hb currently = context)
    for (int t0 = 0; t0 < KL - 1; t0 += TCH) {
        const int Tc = ((KL - 1 - t0) < TCH) ? (KL - 1 - t0) : TCH;
        // featc rows (tl*128+b): cols [0,512) = e_t, cols [512,1536) = h2
        gather_emb<<<(Tc * KB * 64) / 256, 256, 0, stream>>>(emb_dec, seq, featc, KE + KH, t0);
        // gi = e @ W_ih_d[:, :E]^T  (bias lives in ci) -> bf16
        gemm128<<<dim3(KH3 / 128, (Tc * KB) / 128), 256, 0, stream>>>(
            featc, KE + KH, Wb_ih_d, KE + KH, nullptr, gi, KH3, KE, nullptr, nullptr, 0, 0);
        for (int tl = 0; tl < Tc; ++tl) {
            rec_gemm<<<KH3 / 32, 256, 0, stream>>>(hb, Wb_hh_d, gh, KH3, KH, b_hh_d);
            gru_ew<<<(KB * KH) / 256, 256, 0, stream>>>(
                h, hb, gi + (size_t)tl * KB * KH3, ci, gh,
                featc + (size_t)tl * KB * (KE + KH) + KE);
        }
        // preds = [e, h2] @ fc_W[:, :E+H]^T + cf  (K=1536, scatter rows t0+tl+1)
        gemm128<<<dim3(KV / 128, (Tc * KB) / 128), 256, 0, stream>>>(
            featc, KE + KH, fc_Wb, KE + 2 * KH, out, nullptr, KV, KE + KH,
            nullptr, cf, 1, t0);
    }
}